// Round 12
// baseline (718.337 us; speedup 1.0000x reference)
//
#include <hip/hip_runtime.h>
#include <math.h>

// B=8, L=1024, BL=8192, D_MODEL=256, D_INNER=512, D_STATE=16, DT_RANK=16
// Scan: 64 chunks x 16 steps: scan_local + carry + parallel scan_corr.
// Big GEMMs: 64x64-tile LDS-staged MFMA. xproj: direct 1-wave MFMA (N=48).
// dt: vectorized elementwise rank-16 dot + softplus (NOT a GEMM - K=32 too small).

#define CH 64  // chunks
#define CT 16  // steps per chunk

typedef __attribute__((ext_vector_type(8))) short bfrag8;
typedef __attribute__((ext_vector_type(4))) float floatx4;

__device__ __forceinline__ float silu_f(float x) { return x / (1.f + __expf(-x)); }
__device__ __forceinline__ unsigned short f2bf(float x) {
    union { float f; unsigned int u; } c; c.f = x;
    unsigned int r = (c.u + 0x7fffu + ((c.u >> 16) & 1u)) >> 16;
    return (unsigned short)r;
}
__device__ __forceinline__ float bf2f(unsigned short u) {
    union { unsigned int u; float f; } c; c.u = ((unsigned int)u) << 16; return c.f;
}
__device__ __forceinline__ floatx4 exp4(floatx4 x) {
    floatx4 r;
    r[0] = __expf(x[0]); r[1] = __expf(x[1]); r[2] = __expf(x[2]); r[3] = __expf(x[3]);
    return r;
}

// ---- fused multi-job f32->bf16 convert ----
#define NJOBS 6
struct CvtJobs {
    const float* src[NJOBS];
    unsigned short* dst[NJOBS];
    int n_tot[NJOBS];
    int start_blk[NJOBS + 1];
};
__global__ void conv_bf16_multi(CvtJobs J)
{
    int blk = blockIdx.x;
    int job = 0;
    while (job + 1 < NJOBS && blk >= J.start_blk[job + 1]) job++;
    int i = (blk - J.start_blk[job]) * 1024 + threadIdx.x * 4;
    if (i >= J.n_tot[job]) return;
    const float* src = J.src[job];
    unsigned short* dst = J.dst[job];
    float4 v = *(const float4*)(src + i);
    dst[i] = f2bf(v.x); dst[i+1] = f2bf(v.y); dst[i+2] = f2bf(v.z); dst[i+3] = f2bf(v.w);
}

// row-strided pad convert: dst[row*cd + c] = c<cs ? bf(src[row*cs+c]) : 0
__global__ void pad_bf16_kernel(const float* __restrict__ src, unsigned short* __restrict__ dst,
                                int rows, int cs, int cd)
{
    int i = blockIdx.x * 256 + threadIdx.x;
    if (i >= rows * cd) return;
    int row = i / cd, c = i - row * cd;
    dst[i] = (c < cs) ? f2bf(src[row * cs + c]) : (unsigned short)0;
}

// ---- LDS-staged MFMA GEMM: block = 2x2 waves, wave tile = (FR*16)x(FC*16) ----
template<int FR, int FC>
__global__ __launch_bounds__(256)
void smfma_gemm(const unsigned short* __restrict__ A, int lda,
                const unsigned short* __restrict__ W, int ldw,
                int K, const float* __restrict__ bias, const float* __restrict__ Cin,
                float* __restrict__ Cf32, unsigned short* __restrict__ Cbf16,
                int N, int ldc)
{
    const int BM = 2 * FR * 16, BN = 2 * FC * 16;
    const int AR = BM / 64, WR2 = BN / 64;
    __shared__ unsigned short lsA[BM * 40];
    __shared__ unsigned short lsW[BN * 40];
    int tid = threadIdx.x;
    int lane = tid & 63, wave = tid >> 6;
    int wr = wave >> 1, wc = wave & 1;
    int qm = lane >> 4, lm = lane & 15;
    int m0 = blockIdx.y * BM, n0 = blockIdx.x * BN;

    int srow = tid >> 2;
    int skoff = (tid & 3) * 8;
    const unsigned short* Ag = A + (size_t)(m0 + srow) * lda + skoff;
    const unsigned short* Wg = W + (size_t)(n0 + srow) * ldw + skoff;

    floatx4 acc[FR][FC];
#pragma unroll
    for (int i = 0; i < FR; i++)
#pragma unroll
        for (int j = 0; j < FC; j++) acc[i][j] = (floatx4){0.f, 0.f, 0.f, 0.f};

    for (int k0 = 0; k0 < K; k0 += 32) {
        uint4 av[AR], wv[WR2];
#pragma unroll
        for (int r = 0; r < AR; r++)  av[r] = *(const uint4*)(Ag + (size_t)(r * 64) * lda + k0);
#pragma unroll
        for (int r = 0; r < WR2; r++) wv[r] = *(const uint4*)(Wg + (size_t)(r * 64) * ldw + k0);
        __syncthreads();
#pragma unroll
        for (int r = 0; r < AR; r++)  *(uint4*)&lsA[(srow + r * 64) * 40 + skoff] = av[r];
#pragma unroll
        for (int r = 0; r < WR2; r++) *(uint4*)&lsW[(srow + r * 64) * 40 + skoff] = wv[r];
        __syncthreads();
        bfrag8 af[FR], wf[FC];
#pragma unroll
        for (int i = 0; i < FR; i++)
            af[i] = *(bfrag8*)&lsA[(wr * FR * 16 + i * 16 + lm) * 40 + qm * 8];
#pragma unroll
        for (int j = 0; j < FC; j++)
            wf[j] = *(bfrag8*)&lsW[(wc * FC * 16 + j * 16 + lm) * 40 + qm * 8];
#pragma unroll
        for (int i = 0; i < FR; i++)
#pragma unroll
            for (int j = 0; j < FC; j++)
                acc[i][j] = __builtin_amdgcn_mfma_f32_16x16x32_bf16(af[i], wf[j], acc[i][j], 0, 0, 0);
    }

#pragma unroll
    for (int i = 0; i < FR; i++) {
        int mrow = m0 + wr * FR * 16 + i * 16 + qm * 4;
#pragma unroll
        for (int j = 0; j < FC; j++) {
            int n = n0 + wc * FC * 16 + j * 16 + lm;
            if (n < N) {
#pragma unroll
                for (int r = 0; r < 4; r++) {
                    float v = acc[i][j][r];
                    size_t o = (size_t)(mrow + r) * ldc + n;
                    if (bias) v += bias[n];
                    if (Cin) v += Cin[o];
                    if (Cf32) Cf32[o] = v;
                    if (Cbf16) Cbf16[o] = f2bf(v);
                }
            }
        }
    }
}

// ---- direct-from-global MFMA GEMM, ONE WAVE per block (xproj N=48) ----
template<int RM, int RN>
__global__ __launch_bounds__(64)
void dmfma_gemm(const unsigned short* __restrict__ A, int lda,
                const unsigned short* __restrict__ W, int ldw,
                int K, const float* __restrict__ bias, const float* __restrict__ Cin,
                float* __restrict__ Cf32, unsigned short* __restrict__ Cbf16,
                int N, int ldc)
{
    int lane = threadIdx.x;
    int lm = lane & 15, qk = lane >> 4;
    int m0 = blockIdx.y * (16 * RM);
    int n0 = blockIdx.x * (16 * RN);

    const unsigned short* Ab = A + (size_t)(m0 + lm) * lda + qk * 8;
    const unsigned short* Wb = W + (size_t)(n0 + lm) * ldw + qk * 8;

    floatx4 acc[RM][RN];
#pragma unroll
    for (int i = 0; i < RM; i++)
#pragma unroll
        for (int j = 0; j < RN; j++) acc[i][j] = (floatx4){0.f, 0.f, 0.f, 0.f};

    bfrag8 af[RM], wf[RN];
#pragma unroll
    for (int i = 0; i < RM; i++) af[i] = *(const bfrag8*)(Ab + (size_t)i * 16 * lda);
#pragma unroll
    for (int j = 0; j < RN; j++) wf[j] = *(const bfrag8*)(Wb + (size_t)j * 16 * ldw);

    for (int k0 = 32; k0 < K; k0 += 32) {
        bfrag8 afn[RM], wfn[RN];
#pragma unroll
        for (int i = 0; i < RM; i++) afn[i] = *(const bfrag8*)(Ab + (size_t)i * 16 * lda + k0);
#pragma unroll
        for (int j = 0; j < RN; j++) wfn[j] = *(const bfrag8*)(Wb + (size_t)j * 16 * ldw + k0);
#pragma unroll
        for (int i = 0; i < RM; i++)
#pragma unroll
            for (int j = 0; j < RN; j++)
                acc[i][j] = __builtin_amdgcn_mfma_f32_16x16x32_bf16(af[i], wf[j], acc[i][j], 0, 0, 0);
#pragma unroll
        for (int i = 0; i < RM; i++) af[i] = afn[i];
#pragma unroll
        for (int j = 0; j < RN; j++) wf[j] = wfn[j];
    }
#pragma unroll
    for (int i = 0; i < RM; i++)
#pragma unroll
        for (int j = 0; j < RN; j++)
            acc[i][j] = __builtin_amdgcn_mfma_f32_16x16x32_bf16(af[i], wf[j], acc[i][j], 0, 0, 0);

#pragma unroll
    for (int i = 0; i < RM; i++) {
        int mrow = m0 + i * 16 + qk * 4;
#pragma unroll
        for (int j = 0; j < RN; j++) {
            int n = n0 + j * 16 + lm;
            if (n < N) {
#pragma unroll
                for (int r = 0; r < 4; r++) {
                    float v = acc[i][j][r];
                    size_t o = (size_t)(mrow + r) * ldc + n;
                    if (bias) v += bias[n];
                    if (Cin) v += Cin[o];
                    if (Cf32) Cf32[o] = v;
                    if (Cbf16) Cbf16[o] = f2bf(v);
                }
            }
        }
    }
}

// ---- dt: rank-16 dot + softplus, vectorized elementwise ----
// thread = (bt, d4): 4 outputs. dbl row (f32, 64 B) broadcast across 128 threads.
__global__ void dt_kernel(const float* __restrict__ dbl, const float* __restrict__ dtW,
                          const float* __restrict__ dtbias, unsigned short* __restrict__ dt)
{
    int idx = blockIdx.x * 256 + threadIdx.x;
    int d4 = (idx & 127) << 2;
    int bt = idx >> 7;
    const float* r = dbl + (size_t)bt * 48;
    floatx4 r0 = *(const floatx4*)(r);
    floatx4 r1 = *(const floatx4*)(r + 4);
    floatx4 r2 = *(const floatx4*)(r + 8);
    floatx4 r3 = *(const floatx4*)(r + 12);
    ushort4 o;
    unsigned short* op = (unsigned short*)&o;
#pragma unroll
    for (int j = 0; j < 4; j++) {
        const float* w = dtW + (d4 + j) * 16;
        floatx4 a4 = r0 * *(const floatx4*)(w) + r1 * *(const floatx4*)(w + 4)
                   + r2 * *(const floatx4*)(w + 8) + r3 * *(const floatx4*)(w + 12);
        float acc = a4[0] + a4[1] + a4[2] + a4[3] + dtbias[d4 + j];
        acc = fmaxf(acc, 0.f) + log1pf(__expf(-fabsf(acc)));
        op[j] = f2bf(acc);
    }
    *(ushort4*)(dt + (size_t)bt * 512 + d4) = o;
}

// LayerNorm over last dim (256): one WAVE per row, float4 per lane, no LDS.
__global__ void ln_kernel(const float* __restrict__ x, const float* __restrict__ g,
                          const float* __restrict__ b, float* __restrict__ yf,
                          unsigned short* __restrict__ ybf)
{
    int row = blockIdx.x * 4 + (threadIdx.x >> 6);
    int lane = threadIdx.x & 63;
    size_t o = (size_t)row * 256 + lane * 4;
    floatx4 v = *(const floatx4*)(x + o);
    float s1 = v[0] + v[1] + v[2] + v[3];
    float s2 = v[0]*v[0] + v[1]*v[1] + v[2]*v[2] + v[3]*v[3];
#pragma unroll
    for (int off = 1; off < 64; off <<= 1) {
        s1 += __shfl_xor(s1, off);
        s2 += __shfl_xor(s2, off);
    }
    float mu = s1 * (1.f / 256.f);
    float var = s2 * (1.f / 256.f) - mu * mu;
    float rs = rsqrtf(var + 1e-5f);
    floatx4 gv = *(const floatx4*)(g + lane * 4);
    floatx4 bv = *(const floatx4*)(b + lane * 4);
    floatx4 out = (v - mu) * rs * gv + bv;
    if (yf) *(floatx4*)(yf + o) = out;
    if (ybf) {
        ushort4 pk;
        pk.x = f2bf(out[0]); pk.y = f2bf(out[1]); pk.z = f2bf(out[2]); pk.w = f2bf(out[3]);
        *(ushort4*)(ybf + o) = pk;
    }
}

// Causal depthwise conv (k=4) + bias + silu; 4 consecutive d per thread.
__global__ void conv_silu_kernel(const unsigned short* __restrict__ xz, const float* __restrict__ cw,
                                 const float* __restrict__ cb, unsigned short* __restrict__ xc)
{
    int idx = blockIdx.x * 256 + threadIdx.x;
    int d4 = (idx & 127) << 2;
    int bt = idx >> 7;
    int t = bt & 1023;
    floatx4 acc = *(const floatx4*)(cb + d4);
    floatx4 w0 = *(const floatx4*)(cw + d4 * 4);
    floatx4 w1 = *(const floatx4*)(cw + d4 * 4 + 4);
    floatx4 w2 = *(const floatx4*)(cw + d4 * 4 + 8);
    floatx4 w3 = *(const floatx4*)(cw + d4 * 4 + 12);
#pragma unroll
    for (int j = 0; j < 4; j++) {
        int tt = t + j - 3;
        if (tt >= 0) {
            ushort4 v = *(const ushort4*)(xz + (size_t)(bt + j - 3) * 1024 + d4);
            acc[0] += bf2f(v.x) * w0[j];
            acc[1] += bf2f(v.y) * w1[j];
            acc[2] += bf2f(v.z) * w2[j];
            acc[3] += bf2f(v.w) * w3[j];
        }
    }
    ushort4 o;
    o.x = f2bf(silu_f(acc[0])); o.y = f2bf(silu_f(acc[1]));
    o.z = f2bf(silu_f(acc[2])); o.w = f2bf(silu_f(acc[3]));
    *(ushort4*)(xc + (size_t)bt * 512 + d4) = o;
}

// ---- Pass A: local scan from h=0; stores ypart, end-state, dtsum ----
__global__ __launch_bounds__(256, 4)
void scan_local_kernel(const unsigned short* __restrict__ xc, const float* __restrict__ dbl,
                       const unsigned short* __restrict__ dtb, const float* __restrict__ A_log,
                       const float* __restrict__ Dvec,
                       float* __restrict__ dtsums, float* __restrict__ Hbuf,
                       float* __restrict__ ypart)
{
    int bi = blockIdx.x;
    int dgrp = bi & 1;
    int chunk = (bi >> 1) & (CH - 1);
    int b = bi >> 7;
    int d = dgrp * 256 + threadIdx.x;

    floatx4 a0 = -exp4(*(const floatx4*)(A_log + d * 16));
    floatx4 a1 = -exp4(*(const floatx4*)(A_log + d * 16 + 4));
    floatx4 a2 = -exp4(*(const floatx4*)(A_log + d * 16 + 8));
    floatx4 a3 = -exp4(*(const floatx4*)(A_log + d * 16 + 12));
    float dcoef = Dvec[d];

    floatx4 z4 = (floatx4){0.f, 0.f, 0.f, 0.f};
    floatx4 h0 = z4, h1 = z4, h2 = z4, h3 = z4;
    float dtsum = 0.f;

    size_t rbt = (size_t)b * 1024 + chunk * CT;
    float dt_v = bf2f(dtb[rbt * 512 + d]);
    float x_v  = bf2f(xc[rbt * 512 + d]);
    const float* row = dbl + rbt * 48;
    floatx4 B0 = *(const floatx4*)(row + 16);
    floatx4 B1 = *(const floatx4*)(row + 20);
    floatx4 B2 = *(const floatx4*)(row + 24);
    floatx4 B3 = *(const floatx4*)(row + 28);

    for (int t = 0; t < CT - 1; t++) {
        size_t r2 = rbt + 1;
        float dt_n = bf2f(dtb[r2 * 512 + d]);
        float x_n  = bf2f(xc[r2 * 512 + d]);
        const float* rown = dbl + r2 * 48;
        floatx4 Bn0 = *(const floatx4*)(rown + 16);
        floatx4 Bn1 = *(const floatx4*)(rown + 20);
        floatx4 Bn2 = *(const floatx4*)(rown + 24);
        floatx4 Bn3 = *(const floatx4*)(rown + 28);

        float dtx = dt_v * x_v;
        dtsum += dt_v;
        floatx4 dA;
        dA = exp4(dt_v * a0); h0 = h0 * dA + dtx * B0;
        dA = exp4(dt_v * a1); h1 = h1 * dA + dtx * B1;
        dA = exp4(dt_v * a2); h2 = h2 * dA + dtx * B2;
        dA = exp4(dt_v * a3); h3 = h3 * dA + dtx * B3;
        floatx4 C0 = *(const floatx4*)(row + 32);
        floatx4 C1 = *(const floatx4*)(row + 36);
        floatx4 C2 = *(const floatx4*)(row + 40);
        floatx4 C3 = *(const floatx4*)(row + 44);
        floatx4 yv = h0 * C0 + h1 * C1 + h2 * C2 + h3 * C3;
        ypart[rbt * 512 + d] = yv[0] + yv[1] + yv[2] + yv[3] + x_v * dcoef;

        dt_v = dt_n; x_v = x_n;
        B0 = Bn0; B1 = Bn1; B2 = Bn2; B3 = Bn3;
        row = rown; rbt = r2;
    }
    {
        float dtx = dt_v * x_v;
        dtsum += dt_v;
        floatx4 dA;
        dA = exp4(dt_v * a0); h0 = h0 * dA + dtx * B0;
        dA = exp4(dt_v * a1); h1 = h1 * dA + dtx * B1;
        dA = exp4(dt_v * a2); h2 = h2 * dA + dtx * B2;
        dA = exp4(dt_v * a3); h3 = h3 * dA + dtx * B3;
        floatx4 C0 = *(const floatx4*)(row + 32);
        floatx4 C1 = *(const floatx4*)(row + 36);
        floatx4 C2 = *(const floatx4*)(row + 40);
        floatx4 C3 = *(const floatx4*)(row + 44);
        floatx4 yv = h0 * C0 + h1 * C1 + h2 * C2 + h3 * C3;
        ypart[rbt * 512 + d] = yv[0] + yv[1] + yv[2] + yv[3] + x_v * dcoef;
    }
    size_t base = (size_t)chunk * 65536 + ((b * 512 + d) * 16);
    *(floatx4*)&Hbuf[base]      = h0;
    *(floatx4*)&Hbuf[base + 4]  = h1;
    *(floatx4*)&Hbuf[base + 8]  = h2;
    *(floatx4*)&Hbuf[base + 12] = h3;
    dtsums[chunk * 4096 + b * 512 + d] = dtsum;
}

// Pass B: sequential combine; Hbuf becomes chunk START state.
__global__ void scan_carry_kernel(const float* __restrict__ dtsums, const float* __restrict__ A_log,
                                  float* __restrict__ Hbuf)
{
    int ch = blockIdx.x * 256 + threadIdx.x;
    int s = ch & 15;
    int bd = ch >> 4;
    int d = bd & 511;
    float a = -__expf(A_log[d * 16 + s]);
    float h = 0.f;
#pragma unroll 8
    for (int c = 0; c < CH; c++) {
        float hl = Hbuf[(size_t)c * 65536 + ch];
        float P = __expf(dtsums[c * 4096 + bd] * a);
        Hbuf[(size_t)c * 65536 + ch] = h;
        h = fmaf(P, h, hl);
    }
}

// Pass C (fully parallel): y = (ypart + C_t.(h0 * exp(a*S_t))) * silu(z).
__global__ __launch_bounds__(256, 4)
void scan_corr_kernel(const unsigned short* __restrict__ dtb, const float* __restrict__ dbl,
                      const unsigned short* __restrict__ xz, const float* __restrict__ ypart,
                      const float* __restrict__ A_log, const float* __restrict__ Hbuf,
                      unsigned short* __restrict__ y)
{
    int bi = blockIdx.x;
    int dgrp = bi & 1;
    int chunk = (bi >> 1) & (CH - 1);
    int b = bi >> 7;
    int d = dgrp * 256 + threadIdx.x;

    floatx4 a0 = -exp4(*(const floatx4*)(A_log + d * 16));
    floatx4 a1 = -exp4(*(const floatx4*)(A_log + d * 16 + 4));
    floatx4 a2 = -exp4(*(const floatx4*)(A_log + d * 16 + 8));
    floatx4 a3 = -exp4(*(const floatx4*)(A_log + d * 16 + 12));

    size_t base = (size_t)chunk * 65536 + ((b * 512 + d) * 16);
    floatx4 h0 = *(const floatx4*)&Hbuf[base];
    floatx4 h1 = *(const floatx4*)&Hbuf[base + 4];
    floatx4 h2 = *(const floatx4*)&Hbuf[base + 8];
    floatx4 h3 = *(const floatx4*)&Hbuf[base + 12];

    float S = 0.f;
    size_t rbt = (size_t)b * 1024 + chunk * CT;
#pragma unroll 4
    for (int t = 0; t < CT; t++, rbt++) {
        float dt_v = bf2f(dtb[rbt * 512 + d]);
        S += dt_v;
        const float* row = dbl + rbt * 48;
        floatx4 C0 = *(const floatx4*)(row + 32);
        floatx4 C1 = *(const floatx4*)(row + 36);
        floatx4 C2 = *(const floatx4*)(row + 40);
        floatx4 C3 = *(const floatx4*)(row + 44);
        floatx4 cv = (h0 * exp4(S * a0)) * C0 + (h1 * exp4(S * a1)) * C1
                   + (h2 * exp4(S * a2)) * C2 + (h3 * exp4(S * a3)) * C3;
        float corr = cv[0] + cv[1] + cv[2] + cv[3];
        float yp = ypart[rbt * 512 + d];
        float z  = bf2f(xz[rbt * 1024 + 512 + d]);
        y[rbt * 512 + d] = f2bf((yp + corr) * silu_f(z));
    }
}

extern "C" void kernel_launch(void* const* d_in, const int* in_sizes, int n_in,
                              void* d_out, int out_size, void* d_ws, size_t ws_size,
                              hipStream_t stream)
{
    const float* wav     = (const float*)d_in[0];
    const float* lib     = (const float*)d_in[1];
    const float* w2v_W   = (const float*)d_in[2];
    const float* w2v_b   = (const float*)d_in[3];
    const float* lib_W   = (const float*)d_in[4];
    const float* lib_b   = (const float*)d_in[5];
    const float* fuse_W  = (const float*)d_in[6];
    const float* fuse_b  = (const float*)d_in[7];
    const float* proj_W  = (const float*)d_in[8];
    const float* proj_b  = (const float*)d_in[9];
    const float* ln_g    = (const float*)d_in[10];
    const float* ln_b    = (const float*)d_in[11];
    const float* in_W    = (const float*)d_in[12];
    const float* conv_W  = (const float*)d_in[13];
    const float* conv_b  = (const float*)d_in[14];
    const float* xproj_W = (const float*)d_in[15];
    const float* dt_W    = (const float*)d_in[16];
    const float* dt_b    = (const float*)d_in[17];
    const float* A_log   = (const float*)d_in[18];
    const float* D_vec   = (const float*)d_in[19];
    const float* out_W   = (const float*)d_in[20];
    const float* fnorm_g = (const float*)d_in[21];
    const float* fnorm_b = (const float*)d_in[22];

    // ---- workspace layout (~100 MB) ----
    char* p = (char*)d_ws;
    float* hbuf = (float*)p;             p += 8192 * 256 * 4;                  // 8 MB
    unsigned short* xz_bf = (unsigned short*)p; p += (size_t)8192 * 1024 * 2;  // 16 MB
    float* dblb = (float*)p;             p += 8192 * 48 * 4;                   // 1.5 MB
    float* dtsums = (float*)p;           p += (size_t)CH * 4096 * 4;           // 1 MB
    float* Hbuf = (float*)p;             p += (size_t)CH * 65536 * 4;          // 16 MB
    float* ypart = (float*)p;            p += (size_t)8192 * 512 * 4;          // 16 MB
    unsigned short* xln_bf = (unsigned short*)p; p += 8192 * 256 * 2;          // 4 MB
    unsigned short* xcb_bf = (unsigned short*)p; p += 8192 * 512 * 2;          // 8 MB
    unsigned short* dtb_bf = (unsigned short*)p; p += 8192 * 512 * 2;          // 8 MB
    unsigned short* yb_bf  = (unsigned short*)p; p += 8192 * 512 * 2;          // 8 MB
    unsigned short* w2vWb  = (unsigned short*)p; p += 256 * 768 * 2;
    unsigned short* fuseWb = (unsigned short*)p; p += 256 * 512 * 2;
    unsigned short* projWb = (unsigned short*)p; p += 256 * 256 * 2;
    unsigned short* inWb   = (unsigned short*)p; p += 4 * 1024 * 256 * 2;
    unsigned short* outWb  = (unsigned short*)p; p += 4 * 256 * 512 * 2;
    unsigned short* xprojWb= (unsigned short*)p; p += 4 * 64 * 512 * 2;        // rows padded 48->64
    unsigned short* lib_bf = (unsigned short*)p; p += 8192 * 96 * 2;
    unsigned short* libWb  = (unsigned short*)p; p += 256 * 96 * 2;
    // front-end-only overlays (dead during front-end):
    unsigned short* wav_bf  = xcb_bf;   // 12 MB over xcb(8)+dtb(8)
    unsigned short* cat_bf  = yb_bf;    // 8 MB
    unsigned short* fuse_bf = xln_bf;   // 4 MB

    dim3 blk(256);
    dim3 wblk(64);

    // ---- converts ----
    CvtJobs J;
    const float* srcs[NJOBS] = { wav, w2v_W, fuse_W, proj_W, in_W, out_W };
    unsigned short* dsts[NJOBS] = { wav_bf, w2vWb, fuseWb, projWb, inWb, outWb };
    int ntot[NJOBS] = { 6291456, 196608, 131072, 65536, 1048576, 524288 };
    int sb = 0;
    for (int j = 0; j < NJOBS; j++) {
        J.src[j] = srcs[j]; J.dst[j] = dsts[j]; J.n_tot[j] = ntot[j];
        J.start_blk[j] = sb; sb += ntot[j] / 1024;
    }
    J.start_blk[NJOBS] = sb;
    conv_bf16_multi<<<sb, blk, 0, stream>>>(J);
    pad_bf16_kernel<<<(8192 * 96 + 255) / 256, blk, 0, stream>>>(lib, lib_bf, 8192, 93, 96);
    pad_bf16_kernel<<<(256 * 96 + 255) / 256, blk, 0, stream>>>(lib_W, libWb, 256, 93, 96);
    pad_bf16_kernel<<<(4 * 32768 + 255) / 256, blk, 0, stream>>>(xproj_W, xprojWb, 4, 24576, 32768);

    // ---- front-end: 64x64-tile LDS GEMMs ----
    smfma_gemm<2,2><<<dim3(4, 128), blk, 0, stream>>>(wav_bf, 768, w2vWb, 768, 768, w2v_b,
                                                      nullptr, nullptr, cat_bf, 256, 512);
    smfma_gemm<2,2><<<dim3(4, 128), blk, 0, stream>>>(lib_bf, 96, libWb, 96, 96, lib_b,
                                                      nullptr, nullptr, cat_bf + 256, 256, 512);
    smfma_gemm<2,2><<<dim3(4, 128), blk, 0, stream>>>(cat_bf, 512, fuseWb, 512, 512, fuse_b,
                                                      nullptr, nullptr, fuse_bf, 256, 256);
    smfma_gemm<2,2><<<dim3(4, 128), blk, 0, stream>>>(fuse_bf, 256, projWb, 256, 256, proj_b,
                                                      nullptr, hbuf, nullptr, 256, 256);

    for (int i = 0; i < 4; i++) {
        ln_kernel<<<2048, blk, 0, stream>>>(hbuf, ln_g + i * 256, ln_b + i * 256, nullptr, xln_bf);
        smfma_gemm<2,2><<<dim3(16, 128), blk, 0, stream>>>(xln_bf, 256, inWb + (size_t)i * 262144, 256,
                                                           256, nullptr, nullptr, nullptr, xz_bf, 1024, 1024);
        conv_silu_kernel<<<4096, blk, 0, stream>>>(xz_bf, conv_W + i * 2048, conv_b + i * 512, xcb_bf);
        // xproj: N=48, f32 output only
        dmfma_gemm<1,2><<<dim3(2, 512), wblk, 0, stream>>>(xcb_bf, 512, xprojWb + (size_t)i * 32768, 512,
                                                           512, nullptr, nullptr, dblb, nullptr, 48, 48);
        // dt: elementwise rank-16 dot + softplus (f32 inputs)
        dt_kernel<<<4096, blk, 0, stream>>>(dblb, dt_W + i * 8192, dt_b + i * 512, dtb_bf);
        scan_local_kernel<<<1024, blk, 0, stream>>>(xcb_bf, dblb, dtb_bf, A_log + i * 8192,
                                                    D_vec + i * 512, dtsums, Hbuf, ypart);
        scan_carry_kernel<<<256, blk, 0, stream>>>(dtsums, A_log + i * 8192, Hbuf);
        scan_corr_kernel<<<1024, blk, 0, stream>>>(dtb_bf, dblb, xz_bf, ypart,
                                                   A_log + i * 8192, Hbuf, yb_bf);
        smfma_gemm<2,2><<<dim3(4, 128), blk, 0, stream>>>(yb_bf, 512, outWb + (size_t)i * 131072, 512,
                                                          512, nullptr, hbuf, hbuf, nullptr, 256, 256);
    }

    ln_kernel<<<2048, blk, 0, stream>>>(hbuf, fnorm_g, fnorm_b, (float*)d_out, nullptr);
}

// Round 13
// 645.194 us; speedup vs baseline: 1.1134x; 1.1134x over previous
//
#include <hip/hip_runtime.h>
#include <math.h>

// B=8, L=1024, BL=8192, D_MODEL=256, D_INNER=512, D_STATE=16, DT_RANK=16
// Scan: 64 chunks x 16 steps: scan_local + carry + parallel scan_corr.
// Big GEMMs: 64x64-tile LDS-staged MFMA. xproj: direct 1-wave MFMA (N=48).
// dt: persistent-d elementwise - weights in REGISTERS (loaded once/thread),
//     dbl rows broadcast. Fixes round-12's strided weight gather.

#define CH 64  // chunks
#define CT 16  // steps per chunk

typedef __attribute__((ext_vector_type(8))) short bfrag8;
typedef __attribute__((ext_vector_type(4))) float floatx4;

__device__ __forceinline__ float silu_f(float x) { return x / (1.f + __expf(-x)); }
__device__ __forceinline__ unsigned short f2bf(float x) {
    union { float f; unsigned int u; } c; c.f = x;
    unsigned int r = (c.u + 0x7fffu + ((c.u >> 16) & 1u)) >> 16;
    return (unsigned short)r;
}
__device__ __forceinline__ float bf2f(unsigned short u) {
    union { unsigned int u; float f; } c; c.u = ((unsigned int)u) << 16; return c.f;
}
__device__ __forceinline__ floatx4 exp4(floatx4 x) {
    floatx4 r;
    r[0] = __expf(x[0]); r[1] = __expf(x[1]); r[2] = __expf(x[2]); r[3] = __expf(x[3]);
    return r;
}

// ---- fused multi-job f32->bf16 convert ----
#define NJOBS 6
struct CvtJobs {
    const float* src[NJOBS];
    unsigned short* dst[NJOBS];
    int n_tot[NJOBS];
    int start_blk[NJOBS + 1];
};
__global__ void conv_bf16_multi(CvtJobs J)
{
    int blk = blockIdx.x;
    int job = 0;
    while (job + 1 < NJOBS && blk >= J.start_blk[job + 1]) job++;
    int i = (blk - J.start_blk[job]) * 1024 + threadIdx.x * 4;
    if (i >= J.n_tot[job]) return;
    const float* src = J.src[job];
    unsigned short* dst = J.dst[job];
    float4 v = *(const float4*)(src + i);
    dst[i] = f2bf(v.x); dst[i+1] = f2bf(v.y); dst[i+2] = f2bf(v.z); dst[i+3] = f2bf(v.w);
}

// row-strided pad convert: dst[row*cd + c] = c<cs ? bf(src[row*cs+c]) : 0
__global__ void pad_bf16_kernel(const float* __restrict__ src, unsigned short* __restrict__ dst,
                                int rows, int cs, int cd)
{
    int i = blockIdx.x * 256 + threadIdx.x;
    if (i >= rows * cd) return;
    int row = i / cd, c = i - row * cd;
    dst[i] = (c < cs) ? f2bf(src[row * cs + c]) : (unsigned short)0;
}

// ---- LDS-staged MFMA GEMM: block = 2x2 waves, wave tile = (FR*16)x(FC*16) ----
template<int FR, int FC>
__global__ __launch_bounds__(256)
void smfma_gemm(const unsigned short* __restrict__ A, int lda,
                const unsigned short* __restrict__ W, int ldw,
                int K, const float* __restrict__ bias, const float* __restrict__ Cin,
                float* __restrict__ Cf32, unsigned short* __restrict__ Cbf16,
                int N, int ldc)
{
    const int BM = 2 * FR * 16, BN = 2 * FC * 16;
    const int AR = BM / 64, WR2 = BN / 64;
    __shared__ unsigned short lsA[BM * 40];
    __shared__ unsigned short lsW[BN * 40];
    int tid = threadIdx.x;
    int lane = tid & 63, wave = tid >> 6;
    int wr = wave >> 1, wc = wave & 1;
    int qm = lane >> 4, lm = lane & 15;
    int m0 = blockIdx.y * BM, n0 = blockIdx.x * BN;

    int srow = tid >> 2;
    int skoff = (tid & 3) * 8;
    const unsigned short* Ag = A + (size_t)(m0 + srow) * lda + skoff;
    const unsigned short* Wg = W + (size_t)(n0 + srow) * ldw + skoff;

    floatx4 acc[FR][FC];
#pragma unroll
    for (int i = 0; i < FR; i++)
#pragma unroll
        for (int j = 0; j < FC; j++) acc[i][j] = (floatx4){0.f, 0.f, 0.f, 0.f};

    for (int k0 = 0; k0 < K; k0 += 32) {
        uint4 av[AR], wv[WR2];
#pragma unroll
        for (int r = 0; r < AR; r++)  av[r] = *(const uint4*)(Ag + (size_t)(r * 64) * lda + k0);
#pragma unroll
        for (int r = 0; r < WR2; r++) wv[r] = *(const uint4*)(Wg + (size_t)(r * 64) * ldw + k0);
        __syncthreads();
#pragma unroll
        for (int r = 0; r < AR; r++)  *(uint4*)&lsA[(srow + r * 64) * 40 + skoff] = av[r];
#pragma unroll
        for (int r = 0; r < WR2; r++) *(uint4*)&lsW[(srow + r * 64) * 40 + skoff] = wv[r];
        __syncthreads();
        bfrag8 af[FR], wf[FC];
#pragma unroll
        for (int i = 0; i < FR; i++)
            af[i] = *(bfrag8*)&lsA[(wr * FR * 16 + i * 16 + lm) * 40 + qm * 8];
#pragma unroll
        for (int j = 0; j < FC; j++)
            wf[j] = *(bfrag8*)&lsW[(wc * FC * 16 + j * 16 + lm) * 40 + qm * 8];
#pragma unroll
        for (int i = 0; i < FR; i++)
#pragma unroll
            for (int j = 0; j < FC; j++)
                acc[i][j] = __builtin_amdgcn_mfma_f32_16x16x32_bf16(af[i], wf[j], acc[i][j], 0, 0, 0);
    }

#pragma unroll
    for (int i = 0; i < FR; i++) {
        int mrow = m0 + wr * FR * 16 + i * 16 + qm * 4;
#pragma unroll
        for (int j = 0; j < FC; j++) {
            int n = n0 + wc * FC * 16 + j * 16 + lm;
            if (n < N) {
#pragma unroll
                for (int r = 0; r < 4; r++) {
                    float v = acc[i][j][r];
                    size_t o = (size_t)(mrow + r) * ldc + n;
                    if (bias) v += bias[n];
                    if (Cin) v += Cin[o];
                    if (Cf32) Cf32[o] = v;
                    if (Cbf16) Cbf16[o] = f2bf(v);
                }
            }
        }
    }
}

// ---- direct-from-global MFMA GEMM, ONE WAVE per block (xproj N=48) ----
template<int RM, int RN>
__global__ __launch_bounds__(64)
void dmfma_gemm(const unsigned short* __restrict__ A, int lda,
                const unsigned short* __restrict__ W, int ldw,
                int K, const float* __restrict__ bias, const float* __restrict__ Cin,
                float* __restrict__ Cf32, unsigned short* __restrict__ Cbf16,
                int N, int ldc)
{
    int lane = threadIdx.x;
    int lm = lane & 15, qk = lane >> 4;
    int m0 = blockIdx.y * (16 * RM);
    int n0 = blockIdx.x * (16 * RN);

    const unsigned short* Ab = A + (size_t)(m0 + lm) * lda + qk * 8;
    const unsigned short* Wb = W + (size_t)(n0 + lm) * ldw + qk * 8;

    floatx4 acc[RM][RN];
#pragma unroll
    for (int i = 0; i < RM; i++)
#pragma unroll
        for (int j = 0; j < RN; j++) acc[i][j] = (floatx4){0.f, 0.f, 0.f, 0.f};

    bfrag8 af[RM], wf[RN];
#pragma unroll
    for (int i = 0; i < RM; i++) af[i] = *(const bfrag8*)(Ab + (size_t)i * 16 * lda);
#pragma unroll
    for (int j = 0; j < RN; j++) wf[j] = *(const bfrag8*)(Wb + (size_t)j * 16 * ldw);

    for (int k0 = 32; k0 < K; k0 += 32) {
        bfrag8 afn[RM], wfn[RN];
#pragma unroll
        for (int i = 0; i < RM; i++) afn[i] = *(const bfrag8*)(Ab + (size_t)i * 16 * lda + k0);
#pragma unroll
        for (int j = 0; j < RN; j++) wfn[j] = *(const bfrag8*)(Wb + (size_t)j * 16 * ldw + k0);
#pragma unroll
        for (int i = 0; i < RM; i++)
#pragma unroll
            for (int j = 0; j < RN; j++)
                acc[i][j] = __builtin_amdgcn_mfma_f32_16x16x32_bf16(af[i], wf[j], acc[i][j], 0, 0, 0);
#pragma unroll
        for (int i = 0; i < RM; i++) af[i] = afn[i];
#pragma unroll
        for (int j = 0; j < RN; j++) wf[j] = wfn[j];
    }
#pragma unroll
    for (int i = 0; i < RM; i++)
#pragma unroll
        for (int j = 0; j < RN; j++)
            acc[i][j] = __builtin_amdgcn_mfma_f32_16x16x32_bf16(af[i], wf[j], acc[i][j], 0, 0, 0);

#pragma unroll
    for (int i = 0; i < RM; i++) {
        int mrow = m0 + i * 16 + qk * 4;
#pragma unroll
        for (int j = 0; j < RN; j++) {
            int n = n0 + j * 16 + lm;
            if (n < N) {
#pragma unroll
                for (int r = 0; r < 4; r++) {
                    float v = acc[i][j][r];
                    size_t o = (size_t)(mrow + r) * ldc + n;
                    if (bias) v += bias[n];
                    if (Cin) v += Cin[o];
                    if (Cf32) Cf32[o] = v;
                    if (Cbf16) Cbf16[o] = f2bf(v);
                }
            }
        }
    }
}

// ---- dt: persistent-d rank-16 dot + softplus ----
// Block bi: bt in [bi*8, bi*8+8). Thread t owns d = t and d = t+256.
// Weights loaded ONCE into registers (gather amortized); dbl rows broadcast.
__global__ __launch_bounds__(256)
void dt_kernel(const float* __restrict__ dbl, const float* __restrict__ dtW,
               const float* __restrict__ dtbias, unsigned short* __restrict__ dt)
{
    int t = threadIdx.x;
    int bt0 = blockIdx.x * 8;
    floatx4 wa0 = *(const floatx4*)(dtW + t * 16);
    floatx4 wa1 = *(const floatx4*)(dtW + t * 16 + 4);
    floatx4 wa2 = *(const floatx4*)(dtW + t * 16 + 8);
    floatx4 wa3 = *(const floatx4*)(dtW + t * 16 + 12);
    floatx4 wb0 = *(const floatx4*)(dtW + (t + 256) * 16);
    floatx4 wb1 = *(const floatx4*)(dtW + (t + 256) * 16 + 4);
    floatx4 wb2 = *(const floatx4*)(dtW + (t + 256) * 16 + 8);
    floatx4 wb3 = *(const floatx4*)(dtW + (t + 256) * 16 + 12);
    float ba = dtbias[t];
    float bb = dtbias[t + 256];
#pragma unroll
    for (int j = 0; j < 8; j++) {
        size_t bt = bt0 + j;
        const float* r = dbl + bt * 48;
        floatx4 r0 = *(const floatx4*)(r);
        floatx4 r1 = *(const floatx4*)(r + 4);
        floatx4 r2 = *(const floatx4*)(r + 8);
        floatx4 r3 = *(const floatx4*)(r + 12);
        floatx4 da = r0 * wa0 + r1 * wa1 + r2 * wa2 + r3 * wa3;
        floatx4 db = r0 * wb0 + r1 * wb1 + r2 * wb2 + r3 * wb3;
        float va = da[0] + da[1] + da[2] + da[3] + ba;
        float vb = db[0] + db[1] + db[2] + db[3] + bb;
        va = fmaxf(va, 0.f) + log1pf(__expf(-fabsf(va)));
        vb = fmaxf(vb, 0.f) + log1pf(__expf(-fabsf(vb)));
        dt[bt * 512 + t]       = f2bf(va);
        dt[bt * 512 + 256 + t] = f2bf(vb);
    }
}

// LayerNorm over last dim (256): one WAVE per row, float4 per lane, no LDS.
__global__ void ln_kernel(const float* __restrict__ x, const float* __restrict__ g,
                          const float* __restrict__ b, float* __restrict__ yf,
                          unsigned short* __restrict__ ybf)
{
    int row = blockIdx.x * 4 + (threadIdx.x >> 6);
    int lane = threadIdx.x & 63;
    size_t o = (size_t)row * 256 + lane * 4;
    floatx4 v = *(const floatx4*)(x + o);
    float s1 = v[0] + v[1] + v[2] + v[3];
    float s2 = v[0]*v[0] + v[1]*v[1] + v[2]*v[2] + v[3]*v[3];
#pragma unroll
    for (int off = 1; off < 64; off <<= 1) {
        s1 += __shfl_xor(s1, off);
        s2 += __shfl_xor(s2, off);
    }
    float mu = s1 * (1.f / 256.f);
    float var = s2 * (1.f / 256.f) - mu * mu;
    float rs = rsqrtf(var + 1e-5f);
    floatx4 gv = *(const floatx4*)(g + lane * 4);
    floatx4 bv = *(const floatx4*)(b + lane * 4);
    floatx4 out = (v - mu) * rs * gv + bv;
    if (yf) *(floatx4*)(yf + o) = out;
    if (ybf) {
        ushort4 pk;
        pk.x = f2bf(out[0]); pk.y = f2bf(out[1]); pk.z = f2bf(out[2]); pk.w = f2bf(out[3]);
        *(ushort4*)(ybf + o) = pk;
    }
}

// Causal depthwise conv (k=4) + bias + silu; 4 consecutive d per thread.
__global__ void conv_silu_kernel(const unsigned short* __restrict__ xz, const float* __restrict__ cw,
                                 const float* __restrict__ cb, unsigned short* __restrict__ xc)
{
    int idx = blockIdx.x * 256 + threadIdx.x;
    int d4 = (idx & 127) << 2;
    int bt = idx >> 7;
    int t = bt & 1023;
    floatx4 acc = *(const floatx4*)(cb + d4);
    floatx4 w0 = *(const floatx4*)(cw + d4 * 4);
    floatx4 w1 = *(const floatx4*)(cw + d4 * 4 + 4);
    floatx4 w2 = *(const floatx4*)(cw + d4 * 4 + 8);
    floatx4 w3 = *(const floatx4*)(cw + d4 * 4 + 12);
#pragma unroll
    for (int j = 0; j < 4; j++) {
        int tt = t + j - 3;
        if (tt >= 0) {
            ushort4 v = *(const ushort4*)(xz + (size_t)(bt + j - 3) * 1024 + d4);
            acc[0] += bf2f(v.x) * w0[j];
            acc[1] += bf2f(v.y) * w1[j];
            acc[2] += bf2f(v.z) * w2[j];
            acc[3] += bf2f(v.w) * w3[j];
        }
    }
    ushort4 o;
    o.x = f2bf(silu_f(acc[0])); o.y = f2bf(silu_f(acc[1]));
    o.z = f2bf(silu_f(acc[2])); o.w = f2bf(silu_f(acc[3]));
    *(ushort4*)(xc + (size_t)bt * 512 + d4) = o;
}

// ---- Pass A: local scan from h=0; stores ypart, end-state, dtsum ----
__global__ __launch_bounds__(256, 4)
void scan_local_kernel(const unsigned short* __restrict__ xc, const float* __restrict__ dbl,
                       const unsigned short* __restrict__ dtb, const float* __restrict__ A_log,
                       const float* __restrict__ Dvec,
                       float* __restrict__ dtsums, float* __restrict__ Hbuf,
                       float* __restrict__ ypart)
{
    int bi = blockIdx.x;
    int dgrp = bi & 1;
    int chunk = (bi >> 1) & (CH - 1);
    int b = bi >> 7;
    int d = dgrp * 256 + threadIdx.x;

    floatx4 a0 = -exp4(*(const floatx4*)(A_log + d * 16));
    floatx4 a1 = -exp4(*(const floatx4*)(A_log + d * 16 + 4));
    floatx4 a2 = -exp4(*(const floatx4*)(A_log + d * 16 + 8));
    floatx4 a3 = -exp4(*(const floatx4*)(A_log + d * 16 + 12));
    float dcoef = Dvec[d];

    floatx4 z4 = (floatx4){0.f, 0.f, 0.f, 0.f};
    floatx4 h0 = z4, h1 = z4, h2 = z4, h3 = z4;
    float dtsum = 0.f;

    size_t rbt = (size_t)b * 1024 + chunk * CT;
    float dt_v = bf2f(dtb[rbt * 512 + d]);
    float x_v  = bf2f(xc[rbt * 512 + d]);
    const float* row = dbl + rbt * 48;
    floatx4 B0 = *(const floatx4*)(row + 16);
    floatx4 B1 = *(const floatx4*)(row + 20);
    floatx4 B2 = *(const floatx4*)(row + 24);
    floatx4 B3 = *(const floatx4*)(row + 28);

    for (int t = 0; t < CT - 1; t++) {
        size_t r2 = rbt + 1;
        float dt_n = bf2f(dtb[r2 * 512 + d]);
        float x_n  = bf2f(xc[r2 * 512 + d]);
        const float* rown = dbl + r2 * 48;
        floatx4 Bn0 = *(const floatx4*)(rown + 16);
        floatx4 Bn1 = *(const floatx4*)(rown + 20);
        floatx4 Bn2 = *(const floatx4*)(rown + 24);
        floatx4 Bn3 = *(const floatx4*)(rown + 28);

        float dtx = dt_v * x_v;
        dtsum += dt_v;
        floatx4 dA;
        dA = exp4(dt_v * a0); h0 = h0 * dA + dtx * B0;
        dA = exp4(dt_v * a1); h1 = h1 * dA + dtx * B1;
        dA = exp4(dt_v * a2); h2 = h2 * dA + dtx * B2;
        dA = exp4(dt_v * a3); h3 = h3 * dA + dtx * B3;
        floatx4 C0 = *(const floatx4*)(row + 32);
        floatx4 C1 = *(const floatx4*)(row + 36);
        floatx4 C2 = *(const floatx4*)(row + 40);
        floatx4 C3 = *(const floatx4*)(row + 44);
        floatx4 yv = h0 * C0 + h1 * C1 + h2 * C2 + h3 * C3;
        ypart[rbt * 512 + d] = yv[0] + yv[1] + yv[2] + yv[3] + x_v * dcoef;

        dt_v = dt_n; x_v = x_n;
        B0 = Bn0; B1 = Bn1; B2 = Bn2; B3 = Bn3;
        row = rown; rbt = r2;
    }
    {
        float dtx = dt_v * x_v;
        dtsum += dt_v;
        floatx4 dA;
        dA = exp4(dt_v * a0); h0 = h0 * dA + dtx * B0;
        dA = exp4(dt_v * a1); h1 = h1 * dA + dtx * B1;
        dA = exp4(dt_v * a2); h2 = h2 * dA + dtx * B2;
        dA = exp4(dt_v * a3); h3 = h3 * dA + dtx * B3;
        floatx4 C0 = *(const floatx4*)(row + 32);
        floatx4 C1 = *(const floatx4*)(row + 36);
        floatx4 C2 = *(const floatx4*)(row + 40);
        floatx4 C3 = *(const floatx4*)(row + 44);
        floatx4 yv = h0 * C0 + h1 * C1 + h2 * C2 + h3 * C3;
        ypart[rbt * 512 + d] = yv[0] + yv[1] + yv[2] + yv[3] + x_v * dcoef;
    }
    size_t base = (size_t)chunk * 65536 + ((b * 512 + d) * 16);
    *(floatx4*)&Hbuf[base]      = h0;
    *(floatx4*)&Hbuf[base + 4]  = h1;
    *(floatx4*)&Hbuf[base + 8]  = h2;
    *(floatx4*)&Hbuf[base + 12] = h3;
    dtsums[chunk * 4096 + b * 512 + d] = dtsum;
}

// Pass B: sequential combine; Hbuf becomes chunk START state.
__global__ void scan_carry_kernel(const float* __restrict__ dtsums, const float* __restrict__ A_log,
                                  float* __restrict__ Hbuf)
{
    int ch = blockIdx.x * 256 + threadIdx.x;
    int s = ch & 15;
    int bd = ch >> 4;
    int d = bd & 511;
    float a = -__expf(A_log[d * 16 + s]);
    float h = 0.f;
#pragma unroll 8
    for (int c = 0; c < CH; c++) {
        float hl = Hbuf[(size_t)c * 65536 + ch];
        float P = __expf(dtsums[c * 4096 + bd] * a);
        Hbuf[(size_t)c * 65536 + ch] = h;
        h = fmaf(P, h, hl);
    }
}

// Pass C (fully parallel): y = (ypart + C_t.(h0 * exp(a*S_t))) * silu(z).
__global__ __launch_bounds__(256, 4)
void scan_corr_kernel(const unsigned short* __restrict__ dtb, const float* __restrict__ dbl,
                      const unsigned short* __restrict__ xz, const float* __restrict__ ypart,
                      const float* __restrict__ A_log, const float* __restrict__ Hbuf,
                      unsigned short* __restrict__ y)
{
    int bi = blockIdx.x;
    int dgrp = bi & 1;
    int chunk = (bi >> 1) & (CH - 1);
    int b = bi >> 7;
    int d = dgrp * 256 + threadIdx.x;

    floatx4 a0 = -exp4(*(const floatx4*)(A_log + d * 16));
    floatx4 a1 = -exp4(*(const floatx4*)(A_log + d * 16 + 4));
    floatx4 a2 = -exp4(*(const floatx4*)(A_log + d * 16 + 8));
    floatx4 a3 = -exp4(*(const floatx4*)(A_log + d * 16 + 12));

    size_t base = (size_t)chunk * 65536 + ((b * 512 + d) * 16);
    floatx4 h0 = *(const floatx4*)&Hbuf[base];
    floatx4 h1 = *(const floatx4*)&Hbuf[base + 4];
    floatx4 h2 = *(const floatx4*)&Hbuf[base + 8];
    floatx4 h3 = *(const floatx4*)&Hbuf[base + 12];

    float S = 0.f;
    size_t rbt = (size_t)b * 1024 + chunk * CT;
#pragma unroll 4
    for (int t = 0; t < CT; t++, rbt++) {
        float dt_v = bf2f(dtb[rbt * 512 + d]);
        S += dt_v;
        const float* row = dbl + rbt * 48;
        floatx4 C0 = *(const floatx4*)(row + 32);
        floatx4 C1 = *(const floatx4*)(row + 36);
        floatx4 C2 = *(const floatx4*)(row + 40);
        floatx4 C3 = *(const floatx4*)(row + 44);
        floatx4 cv = (h0 * exp4(S * a0)) * C0 + (h1 * exp4(S * a1)) * C1
                   + (h2 * exp4(S * a2)) * C2 + (h3 * exp4(S * a3)) * C3;
        float corr = cv[0] + cv[1] + cv[2] + cv[3];
        float yp = ypart[rbt * 512 + d];
        float z  = bf2f(xz[rbt * 1024 + 512 + d]);
        y[rbt * 512 + d] = f2bf((yp + corr) * silu_f(z));
    }
}

extern "C" void kernel_launch(void* const* d_in, const int* in_sizes, int n_in,
                              void* d_out, int out_size, void* d_ws, size_t ws_size,
                              hipStream_t stream)
{
    const float* wav     = (const float*)d_in[0];
    const float* lib     = (const float*)d_in[1];
    const float* w2v_W   = (const float*)d_in[2];
    const float* w2v_b   = (const float*)d_in[3];
    const float* lib_W   = (const float*)d_in[4];
    const float* lib_b   = (const float*)d_in[5];
    const float* fuse_W  = (const float*)d_in[6];
    const float* fuse_b  = (const float*)d_in[7];
    const float* proj_W  = (const float*)d_in[8];
    const float* proj_b  = (const float*)d_in[9];
    const float* ln_g    = (const float*)d_in[10];
    const float* ln_b    = (const float*)d_in[11];
    const float* in_W    = (const float*)d_in[12];
    const float* conv_W  = (const float*)d_in[13];
    const float* conv_b  = (const float*)d_in[14];
    const float* xproj_W = (const float*)d_in[15];
    const float* dt_W    = (const float*)d_in[16];
    const float* dt_b    = (const float*)d_in[17];
    const float* A_log   = (const float*)d_in[18];
    const float* D_vec   = (const float*)d_in[19];
    const float* out_W   = (const float*)d_in[20];
    const float* fnorm_g = (const float*)d_in[21];
    const float* fnorm_b = (const float*)d_in[22];

    // ---- workspace layout (~100 MB) ----
    char* p = (char*)d_ws;
    float* hbuf = (float*)p;             p += 8192 * 256 * 4;                  // 8 MB
    unsigned short* xz_bf = (unsigned short*)p; p += (size_t)8192 * 1024 * 2;  // 16 MB
    float* dblb = (float*)p;             p += 8192 * 48 * 4;                   // 1.5 MB
    float* dtsums = (float*)p;           p += (size_t)CH * 4096 * 4;           // 1 MB
    float* Hbuf = (float*)p;             p += (size_t)CH * 65536 * 4;          // 16 MB
    float* ypart = (float*)p;            p += (size_t)8192 * 512 * 4;          // 16 MB
    unsigned short* xln_bf = (unsigned short*)p; p += 8192 * 256 * 2;          // 4 MB
    unsigned short* xcb_bf = (unsigned short*)p; p += 8192 * 512 * 2;          // 8 MB
    unsigned short* dtb_bf = (unsigned short*)p; p += 8192 * 512 * 2;          // 8 MB
    unsigned short* yb_bf  = (unsigned short*)p; p += 8192 * 512 * 2;          // 8 MB
    unsigned short* w2vWb  = (unsigned short*)p; p += 256 * 768 * 2;
    unsigned short* fuseWb = (unsigned short*)p; p += 256 * 512 * 2;
    unsigned short* projWb = (unsigned short*)p; p += 256 * 256 * 2;
    unsigned short* inWb   = (unsigned short*)p; p += 4 * 1024 * 256 * 2;
    unsigned short* outWb  = (unsigned short*)p; p += 4 * 256 * 512 * 2;
    unsigned short* xprojWb= (unsigned short*)p; p += 4 * 64 * 512 * 2;        // rows padded 48->64
    unsigned short* lib_bf = (unsigned short*)p; p += 8192 * 96 * 2;
    unsigned short* libWb  = (unsigned short*)p; p += 256 * 96 * 2;
    // front-end-only overlays (dead during front-end):
    unsigned short* wav_bf  = xcb_bf;   // 12 MB over xcb(8)+dtb(8)
    unsigned short* cat_bf  = yb_bf;    // 8 MB
    unsigned short* fuse_bf = xln_bf;   // 4 MB

    dim3 blk(256);
    dim3 wblk(64);

    // ---- converts ----
    CvtJobs J;
    const float* srcs[NJOBS] = { wav, w2v_W, fuse_W, proj_W, in_W, out_W };
    unsigned short* dsts[NJOBS] = { wav_bf, w2vWb, fuseWb, projWb, inWb, outWb };
    int ntot[NJOBS] = { 6291456, 196608, 131072, 65536, 1048576, 524288 };
    int sb = 0;
    for (int j = 0; j < NJOBS; j++) {
        J.src[j] = srcs[j]; J.dst[j] = dsts[j]; J.n_tot[j] = ntot[j];
        J.start_blk[j] = sb; sb += ntot[j] / 1024;
    }
    J.start_blk[NJOBS] = sb;
    conv_bf16_multi<<<sb, blk, 0, stream>>>(J);
    pad_bf16_kernel<<<(8192 * 96 + 255) / 256, blk, 0, stream>>>(lib, lib_bf, 8192, 93, 96);
    pad_bf16_kernel<<<(256 * 96 + 255) / 256, blk, 0, stream>>>(lib_W, libWb, 256, 93, 96);
    pad_bf16_kernel<<<(4 * 32768 + 255) / 256, blk, 0, stream>>>(xproj_W, xprojWb, 4, 24576, 32768);

    // ---- front-end: 64x64-tile LDS GEMMs ----
    smfma_gemm<2,2><<<dim3(4, 128), blk, 0, stream>>>(wav_bf, 768, w2vWb, 768, 768, w2v_b,
                                                      nullptr, nullptr, cat_bf, 256, 512);
    smfma_gemm<2,2><<<dim3(4, 128), blk, 0, stream>>>(lib_bf, 96, libWb, 96, 96, lib_b,
                                                      nullptr, nullptr, cat_bf + 256, 256, 512);
    smfma_gemm<2,2><<<dim3(4, 128), blk, 0, stream>>>(cat_bf, 512, fuseWb, 512, 512, fuse_b,
                                                      nullptr, nullptr, fuse_bf, 256, 256);
    smfma_gemm<2,2><<<dim3(4, 128), blk, 0, stream>>>(fuse_bf, 256, projWb, 256, 256, proj_b,
                                                      nullptr, hbuf, nullptr, 256, 256);

    for (int i = 0; i < 4; i++) {
        ln_kernel<<<2048, blk, 0, stream>>>(hbuf, ln_g + i * 256, ln_b + i * 256, nullptr, xln_bf);
        smfma_gemm<2,2><<<dim3(16, 128), blk, 0, stream>>>(xln_bf, 256, inWb + (size_t)i * 262144, 256,
                                                           256, nullptr, nullptr, nullptr, xz_bf, 1024, 1024);
        conv_silu_kernel<<<4096, blk, 0, stream>>>(xz_bf, conv_W + i * 2048, conv_b + i * 512, xcb_bf);
        // xproj: N=48, f32 output only
        dmfma_gemm<1,2><<<dim3(2, 512), wblk, 0, stream>>>(xcb_bf, 512, xprojWb + (size_t)i * 32768, 512,
                                                           512, nullptr, nullptr, dblb, nullptr, 48, 48);
        // dt: persistent-d, register weights, broadcast dbl rows
        dt_kernel<<<1024, blk, 0, stream>>>(dblb, dt_W + i * 8192, dt_b + i * 512, dtb_bf);
        scan_local_kernel<<<1024, blk, 0, stream>>>(xcb_bf, dblb, dtb_bf, A_log + i * 8192,
                                                    D_vec + i * 512, dtsums, Hbuf, ypart);
        scan_carry_kernel<<<256, blk, 0, stream>>>(dtsums, A_log + i * 8192, Hbuf);
        scan_corr_kernel<<<1024, blk, 0, stream>>>(dtb_bf, dblb, xz_bf, ypart,
                                                   A_log + i * 8192, Hbuf, yb_bf);
        smfma_gemm<2,2><<<dim3(4, 128), blk, 0, stream>>>(yb_bf, 512, outWb + (size_t)i * 131072, 512,
                                                          512, nullptr, hbuf, hbuf, nullptr, 256, 256);
    }

    ln_kernel<<<2048, blk, 0, stream>>>(hbuf, fnorm_g, fnorm_b, (float*)d_out, nullptr);
}